// Round 5
// baseline (488.716 us; speedup 1.0000x reference)
//
#include <hip/hip_runtime.h>
#include <hip/hip_bf16.h>

// ---------------------------------------------------------------------------
// Swin window MSA, MI355X/gfx950.
// R9: occupancy was REGISTER-bound (VGPR 112 + 128 acc-AGPR = 240 unified ->
// 8 waves = 1 block/CU) — why all R5-R8 schedules pinned at ~33% MfmaUtil:
// every barrier/vmcnt stall fully exposed. Fix: 256x128 tile, 8 waves 4Mx2N,
// per-wave 64x64 output -> acc 64 AGPR; __launch_bounds__(512,4) => 2
// blocks/CU. LDS: 2-slot double buffer (A16K+B8K)*2 = 48 KiB. Schedule =
// T3-minimum (STAGE next / read frags / MFMA x16 / __syncthreads); the
// barrier drain is hidden by the co-resident block (m97 mechanism).
// Kept: T1 XCD-bijective swizzle (m-major), T2 swizzle g(r)=(r>>1)&3 on
// pre-swizzled global source + ds_read addr, setprio around MFMA cluster.
// qkv planes: [which][w][h][tok][d]. attn out: head-blocked [h][w][tok][d].
// ---------------------------------------------------------------------------

typedef unsigned short u16;
typedef __bf16 bx8 __attribute__((ext_vector_type(8)));
typedef float f4_t __attribute__((ext_vector_type(4)));

#define QKV_ELEMS 33554432ull        // 1024*16*64*32 per Q/K/V plane
#define SCALE 0.17677669529663687f   // 32^-0.5

static __device__ __forceinline__ u16 f2b(float f) {
    return __builtin_bit_cast(u16, (__bf16)f);
}

typedef const unsigned int __attribute__((address_space(1)))* gas_t;
typedef unsigned int __attribute__((address_space(3)))* las_t;
static __device__ __forceinline__ void glds16(const void* g, void* l) {
    __builtin_amdgcn_global_load_lds((gas_t)g, (las_t)l, 16, 0, 0);
}

// ---- fused prep: cvt(x->bf16) + W transposes + bias gather ----------------
// blocks [0,16384): x cvt; [16384,19456): qkv_w^T; [19456,20480): proj_w^T;
// [20480,20736): bias_full[h][q][k] = bias_table[rel_index[q*64+k]][h]
__global__ __launch_bounds__(256) void prep_k(
    const float* __restrict__ X, u16* __restrict__ Xb,
    const float* __restrict__ qkv_w, u16* __restrict__ Wt1,
    const float* __restrict__ proj_w, u16* __restrict__ Wt2,
    const float* __restrict__ bias_t, const int* __restrict__ rel,
    float* __restrict__ biasf) {
    const int b = blockIdx.x;
    if (b < 16384) {
        size_t i = ((size_t)b * 256 + threadIdx.x) * 8;
        float4 v0 = *(const float4*)(X + i);
        float4 v1 = *(const float4*)(X + i + 4);
        ushort4 p0, p1;
        p0.x = f2b(v0.x); p0.y = f2b(v0.y); p0.z = f2b(v0.z); p0.w = f2b(v0.w);
        p1.x = f2b(v1.x); p1.y = f2b(v1.y); p1.z = f2b(v1.z); p1.w = f2b(v1.w);
        *(ushort4*)(Xb + i) = p0;
        *(ushort4*)(Xb + i + 4) = p1;
    } else if (b < 16384 + 3072) {
        int idx = (b - 16384) * 256 + threadIdx.x;   // 1536*512
        int n = idx >> 9, k = idx & 511;
        Wt1[idx] = f2b(qkv_w[(size_t)k * 1536 + n]);
    } else if (b < 16384 + 4096) {
        int idx = (b - 16384 - 3072) * 256 + threadIdx.x;  // 512*512
        int n = idx >> 9, k = idx & 511;
        Wt2[idx] = f2b(proj_w[(size_t)k * 512 + n]);
    } else {
        int idx = (b - 16384 - 4096) * 256 + threadIdx.x;  // 16*4096
        int h = idx >> 12, rc = idx & 4095;
        biasf[idx] = bias_t[rel[rc] * 16 + h];
    }
}

// ---- 256x128-tile GEMM, 2 blocks/CU ---------------------------------------
// C = A @ Bt^T (+bias), K=512 fixed (16 K-tiles of 32).
// MODE 0: A = xb row-major MxK; out -> QKV planes bf16.
// MODE 1: A = attn head-blocked [h][w][tok][32] (plane h == K-tile h);
//         out -> fp32 rows (N=512).
template <int MODE>
__global__ __launch_bounds__(512, 4) void gemm_k(
    const u16* __restrict__ A, const u16* __restrict__ Bt,
    const float* __restrict__ bias, void* __restrict__ Out) {
    extern __shared__ __align__(16) char smem[];   // 49152 B dynamic
    const int tid = threadIdx.x;
    const int wave = tid >> 6, lane = tid & 63;
    const int l16 = lane & 15, quad = lane >> 4;
    const int wm = wave >> 1, wn = wave & 1;       // 4M x 2N wave grid

    // T1: bijective XCD swizzle (nwg % 8 == 0), m-major per chunk
    const int NT_COL = (MODE == 0) ? 12 : 4;       // N/128 column tiles
    const int NWG = (MODE == 0) ? 3072 : 1024;
    const int bid = blockIdx.x;
    const int swz = (bid & 7) * (NWG >> 3) + (bid >> 3);
    const int m0 = (swz / NT_COL) << 8;            // 256-row tiles
    const int n0 = (swz % NT_COL) << 7;            // 128-col tiles

    // staging: HW lands lane l at base + l*16 -> row 16*wave + (l>>2),
    // chunk l&3. T2: LDS[row][c] = global[row][c ^ g(row&15)], g(r)=(r>>1)&3.
    const int lr = lane >> 2, lc = lane & 3;
    const int swzc = (lc ^ ((lr >> 1) & 3)) * 8;   // elems
    const int stoff = wave * 1024;                 // wave-uniform LDS base

    const u16* Asrc0;
    const u16* Asrc1;
    if (MODE == 0) {
        Asrc0 = A + (size_t)(m0 + wave * 16 + lr) * 512 + swzc;
        Asrc1 = Asrc0 + (size_t)128 * 512;
    } else {
        const int r0 = m0 + wave * 16 + lr, r1 = r0 + 128;
        Asrc0 = A + (size_t)(r0 >> 6) * 2048 + (r0 & 63) * 32 + swzc;
        Asrc1 = A + (size_t)(r1 >> 6) * 2048 + (r1 & 63) * 32 + swzc;
    }
    const u16* Bsrc0 = Bt + (size_t)(n0 + wave * 16 + lr) * 512 + swzc;

    // slot s: A 16 KB @ s*24576, B 8 KB @ s*24576+16384
    auto STAGE = [&](int T) {
        char* base = smem + (T & 1) * 24576;
        if (MODE == 0) {
            glds16(Asrc0 + (size_t)T * 32, base + stoff);
            glds16(Asrc1 + (size_t)T * 32, base + 8192 + stoff);
        } else {
            glds16(Asrc0 + (size_t)T * 2097152, base + stoff);
            glds16(Asrc1 + (size_t)T * 2097152, base + 8192 + stoff);
        }
        glds16(Bsrc0 + (size_t)T * 32, base + 16384 + stoff);
    };

    // frag read: row = strip*16 + l16, chunk = quad ^ g(l16)
    const int foff = l16 * 64 + ((quad ^ ((l16 >> 1) & 3)) * 16);

    f4_t acc[4][4];
#pragma unroll
    for (int i = 0; i < 4; ++i)
#pragma unroll
        for (int j = 0; j < 4; ++j) acc[i][j] = (f4_t){0.f, 0.f, 0.f, 0.f};

    STAGE(0);
    __syncthreads();   // vmcnt(0) drain + barrier: slot0 ready

    #pragma unroll
    for (int T = 0; T < 16; ++T) {
        if (T < 15) STAGE(T + 1);
        const char* sb = smem + (T & 1) * 24576;
        const char* aT = sb + wm * 4096 + foff;
        const char* bT = sb + 16384 + wn * 4096 + foff;
        bx8 af[4], bf[4];
#pragma unroll
        for (int i = 0; i < 4; ++i) af[i] = *(const bx8*)(aT + i * 1024);
#pragma unroll
        for (int i = 0; i < 4; ++i) bf[i] = *(const bx8*)(bT + i * 1024);
        __builtin_amdgcn_s_setprio(1);
#pragma unroll
        for (int mt = 0; mt < 4; ++mt)
#pragma unroll
            for (int nt = 0; nt < 4; ++nt)
                acc[mt][nt] = __builtin_amdgcn_mfma_f32_16x16x32_bf16(
                    af[mt], bf[nt], acc[mt][nt], 0, 0, 0);
        __builtin_amdgcn_s_setprio(0);
        __syncthreads();   // vmcnt(0): T+1 staged; barrier: slot reuse safe
    }

    float bv[4];
#pragma unroll
    for (int nt = 0; nt < 4; ++nt) bv[nt] = bias[n0 + wn * 64 + nt * 16 + l16];

    if (MODE == 0) {
        // epilogue: 4 passes of 64 rows through LDS; 1024 B/wave stores.
        // column layout is [head][which][d]: 96 = 3*32 cols per head.
        u16* c_s = (u16*)smem;          // [64][132] bf16 (stride: bank-clean)
        u16* qkvp = (u16*)Out;
        const int wwin = m0 >> 6;
#pragma unroll
        for (int p = 0; p < 4; ++p) {
            if (wm == p) {
#pragma unroll
                for (int mt = 0; mt < 4; ++mt)
#pragma unroll
                    for (int nt = 0; nt < 4; ++nt)
#pragma unroll
                        for (int i = 0; i < 4; ++i)
                            c_s[(mt * 16 + quad * 4 + i) * 132 +
                                wn * 64 + nt * 16 + l16] =
                                f2b(acc[mt][nt][i] + bv[nt]);
            }
            __syncthreads();
#pragma unroll
            for (int j = 0; j < 2; ++j) {
                int flat = tid + 512 * j;          // 1024 uint4: 4 col-groups
                int g2 = flat >> 8, idx = flat & 255;
                int tok = idx >> 2, d8 = (idx & 3) * 8;
                int cg = n0 + g2 * 32;
                int hh = cg / 96;
                int which = (cg - hh * 96) >> 5;
                uint4 v = *(const uint4*)&c_s[tok * 132 + g2 * 32 + d8];
                *(uint4*)(qkvp + (size_t)which * QKV_ELEMS +
                          (size_t)hh * 2048 +
                          (size_t)(wwin + p) * 32768 + tok * 32 + d8) = v;
            }
            __syncthreads();
        }
    } else {
        // epilogue: fp32 rows, 4 passes of 64 rows, 128 cols
        float* c_sf = (float*)smem;     // [64][132] fp32
        float* Of = (float*)Out;
#pragma unroll
        for (int p = 0; p < 4; ++p) {
            if (wm == p) {
#pragma unroll
                for (int mt = 0; mt < 4; ++mt)
#pragma unroll
                    for (int nt = 0; nt < 4; ++nt)
#pragma unroll
                        for (int i = 0; i < 4; ++i)
                            c_sf[(mt * 16 + quad * 4 + i) * 132 +
                                 wn * 64 + nt * 16 + l16] =
                                acc[mt][nt][i] + bv[nt];
            }
            __syncthreads();
#pragma unroll
            for (int j = 0; j < 4; ++j) {
                int flat = tid + 512 * j;          // 2048 float4: 64r x 32
                int r = flat >> 5, c4 = (flat & 31) * 4;
                float4 v = *(const float4*)&c_sf[r * 132 + c4];
                *(float4*)&Of[(size_t)(m0 + p * 64 + r) * 512 + n0 + c4] = v;
            }
            __syncthreads();
        }
    }
}

// ---- attention: 1 block per (window, head), 4 waves -----------------------
// LDS total 40704 B -> 4 blocks/CU
__global__ __launch_bounds__(256, 4) void attn_k(
    const u16* __restrict__ qkv, const float* __restrict__ mask,
    const float* __restrict__ biasf, u16* __restrict__ attn_out) {
    const int bx = blockIdx.x;
    const int w = bx >> 4, h = bx & 15;
    const int wmk = w & 255;  // mask window = b % 256
    const int tid = threadIdx.x;
    const int wave = tid >> 6, lane = tid & 63;
    const int quad = lane >> 4, l16 = lane & 15;

    __shared__ alignas(16) u16 q_s[64 * 40];
    __shared__ alignas(16) u16 k_s[64 * 40];
    __shared__ alignas(16) u16 vT[32 * 72];   // vT[d][tok]
    __shared__ alignas(16) float s_s[64 * 65];
    __shared__ alignas(16) u16 p_s[64 * 72];

    const size_t base = (size_t)((w << 4) + h) * 2048;  // 64*32 per (w,h)
    {
        int tok = tid >> 2, d0 = (tid & 3) * 8;
        uint4 qv = *(const uint4*)(qkv + base + tid * 8);
        *(uint4*)&q_s[tok * 40 + d0] = qv;
        uint4 kv = *(const uint4*)(qkv + QKV_ELEMS + base + tid * 8);
        *(uint4*)&k_s[tok * 40 + d0] = kv;
        uint4 vv = *(const uint4*)(qkv + 2 * QKV_ELEMS + base + tid * 8);
        const u16* pv = (const u16*)&vv;
#pragma unroll
        for (int j = 0; j < 8; ++j) vT[(d0 + j) * 72 + tok] = pv[j];
    }
    __syncthreads();

    // S = Q K^T * scale + bias + mask  (wave -> 16-row strip)
    {
        bx8 a = *(const bx8*)&q_s[(wave * 16 + l16) * 40 + quad * 8];
#pragma unroll
        for (int nt = 0; nt < 4; ++nt) {
            bx8 b = *(const bx8*)&k_s[(nt * 16 + l16) * 40 + quad * 8];
            f4_t acc = (f4_t){0.f, 0.f, 0.f, 0.f};
            acc = __builtin_amdgcn_mfma_f32_16x16x32_bf16(a, b, acc, 0, 0, 0);
#pragma unroll
            for (int i = 0; i < 4; ++i) {
                int r = wave * 16 + quad * 4 + i;
                int c = nt * 16 + l16;
                float s = acc[i] * SCALE + biasf[(h << 12) + (r << 6) + c] +
                          mask[((size_t)wmk * 64 + r) * 64 + c];
                s_s[r * 65 + c] = s;
            }
        }
    }
    __syncthreads();

    // row softmax: 4 threads per row, 16 cols each, shuffle-reduce
    {
        int row = tid >> 2, j = (tid & 3) * 16;
        float mx = -1e30f;
#pragma unroll
        for (int cc = 0; cc < 16; ++cc) mx = fmaxf(mx, s_s[row * 65 + j + cc]);
        mx = fmaxf(mx, __shfl_xor(mx, 1));
        mx = fmaxf(mx, __shfl_xor(mx, 2));
        float e[16], sum = 0.f;
#pragma unroll
        for (int cc = 0; cc < 16; ++cc) {
            e[cc] = __expf(s_s[row * 65 + j + cc] - mx);
            sum += e[cc];
        }
        sum += __shfl_xor(sum, 1);
        sum += __shfl_xor(sum, 2);
        float inv = 1.f / sum;
#pragma unroll
        for (int cc = 0; cc < 16; ++cc) p_s[row * 72 + j + cc] = f2b(e[cc] * inv);
    }
    __syncthreads();   // also fences s_s reads; s_s reused as O stage below

    // O = P V ; restage -> head-blocked [h][w][tok][d], coalesced uint4
    {
        u16* os = (u16*)s_s;   // [64][40]
#pragma unroll
        for (int nt = 0; nt < 2; ++nt) {
            f4_t acc = (f4_t){0.f, 0.f, 0.f, 0.f};
#pragma unroll
            for (int ks = 0; ks < 2; ++ks) {
                bx8 a = *(const bx8*)&p_s[(wave * 16 + l16) * 72 + ks * 32 + quad * 8];
                bx8 b = *(const bx8*)&vT[(nt * 16 + l16) * 72 + ks * 32 + quad * 8];
                acc = __builtin_amdgcn_mfma_f32_16x16x32_bf16(a, b, acc, 0, 0, 0);
            }
#pragma unroll
            for (int i = 0; i < 4; ++i)
                os[(wave * 16 + quad * 4 + i) * 40 + nt * 16 + l16] =
                    f2b(acc[i]);
        }
        __syncthreads();
        int tok = tid >> 2, d8 = (tid & 3) * 8;
        uint4 v = *(const uint4*)&os[tok * 40 + d8];
        *(uint4*)(attn_out + ((((size_t)h << 10) + w) << 11) + tid * 8) = v;
    }
}

extern "C" void kernel_launch(void* const* d_in, const int* in_sizes, int n_in,
                              void* d_out, int out_size, void* d_ws,
                              size_t ws_size, hipStream_t stream) {
    const float* x      = (const float*)d_in[0];
    const float* mask   = (const float*)d_in[1];
    const float* qkv_w  = (const float*)d_in[2];
    const float* qkv_b  = (const float*)d_in[3];
    const float* proj_w = (const float*)d_in[4];
    const float* proj_b = (const float*)d_in[5];
    const float* bias_t = (const float*)d_in[6];
    const int*   rel    = (const int*)d_in[7];
    float* out = (float*)d_out;

    char* ws = (char*)d_ws;
    u16* Wt1 = (u16*)ws;      ws += (size_t)1536 * 512 * 2;   // qkv_w^T bf16
    u16* Wt2 = (u16*)ws;      ws += (size_t)512 * 512 * 2;    // proj_w^T bf16
    float* biasf = (float*)ws; ws += (size_t)16 * 64 * 64 * 4; // bias_full
    u16* qkv = (u16*)ws;      ws += 3 * QKV_ELEMS * 2;        // Q,K,V planes
    u16* attn = (u16*)ws;     ws += QKV_ELEMS * 2;            // attn out bf16
    u16* xb = attn;  // alias: x_bf16 used only before attn_out is written

    // fused prep: cvt + qkv_w^T + proj_w^T + bias (16384+3072+1024+256)
    prep_k<<<20736, 256, 0, stream>>>(x, xb, qkv_w, Wt1, proj_w, Wt2,
                                      bias_t, rel, biasf);
    // QKV projection: M=65536, N=1536, K=512 (256x128 tiles)
    gemm_k<0><<<3072, 512, 49152, stream>>>(xb, Wt1, qkv_b, qkv);
    // window attention: 1024 windows x 16 heads
    attn_k<<<16384, 256, 0, stream>>>(qkv, mask, biasf, attn);
    // output projection: M=65536, N=512, K=512 (256x128 tiles)
    gemm_k<1><<<1024, 512, 49152, stream>>>(attn, Wt2, proj_b, out);
}

// Round 8
// 482.891 us; speedup vs baseline: 1.0121x; 1.0121x over previous
//
#include <hip/hip_runtime.h>
#include <hip/hip_bf16.h>

// ---------------------------------------------------------------------------
// Swin window MSA, MI355X/gfx950.
// R10 (3rd submit; prior two were GPUAcquisitionTimeout — never measured).
// BK=64 GEMM, sync-density cut. R9 taught: occupancy isn't the lever
// (2 blk/CU + 0 conflicts was SLOWER); sync events per K are. New: 256x256,
// BK=64, 2-slot dbuf (128 KB), 8 waves 2Mx4N (128x64/wave = best
// reads/MFMA). Per 64-K tile: 4 phases x 16 MFMA, rotating counted
// lgkmcnt(4/8) operand prefetch (always >=1 phase ahead), ONE vmcnt(0) +
// ONE barrier (issued 3 phases after the stage -> drain cheap). 4x fewer
// barriers, 2x fewer vmcnt per K than R7. 128-B LDS rows: swizzle c^=row&7
// on glds source + ds_read (both sides). MODE1 tile spans 2 head-planes:
// per-lane plane-select offset.
// History: R5 256² 4-barrier (175->142), R6 swizzle fix (conflicts
// 1.1e7->1.6e6, 136), R7 pipelined lgkm (130-134), R9 256x128 2blk/CU
// regression (153, MfmaUtil 29%).
// qkv planes: [which][w][h][tok][d]. attn out: head-blocked [h][w][tok][d].
// ---------------------------------------------------------------------------

typedef unsigned short u16;
typedef __bf16 bx8 __attribute__((ext_vector_type(8)));
typedef float f4_t __attribute__((ext_vector_type(4)));

#define QKV_ELEMS 33554432ull        // 1024*16*64*32 per Q/K/V plane
#define SCALE 0.17677669529663687f   // 32^-0.5

static __device__ __forceinline__ u16 f2b(float f) {
    return __builtin_bit_cast(u16, (__bf16)f);
}

typedef const unsigned int __attribute__((address_space(1)))* gas_t;
typedef unsigned int __attribute__((address_space(3)))* las_t;
static __device__ __forceinline__ void glds16(const void* g, void* l) {
    __builtin_amdgcn_global_load_lds((gas_t)g, (las_t)l, 16, 0, 0);
}

// ---- fused prep: cvt(x->bf16) + W transposes + bias gather ----------------
__global__ __launch_bounds__(256) void prep_k(
    const float* __restrict__ X, u16* __restrict__ Xb,
    const float* __restrict__ qkv_w, u16* __restrict__ Wt1,
    const float* __restrict__ proj_w, u16* __restrict__ Wt2,
    const float* __restrict__ bias_t, const int* __restrict__ rel,
    float* __restrict__ biasf) {
    const int b = blockIdx.x;
    if (b < 16384) {
        size_t i = ((size_t)b * 256 + threadIdx.x) * 8;
        float4 v0 = *(const float4*)(X + i);
        float4 v1 = *(const float4*)(X + i + 4);
        ushort4 p0, p1;
        p0.x = f2b(v0.x); p0.y = f2b(v0.y); p0.z = f2b(v0.z); p0.w = f2b(v0.w);
        p1.x = f2b(v1.x); p1.y = f2b(v1.y); p1.z = f2b(v1.z); p1.w = f2b(v1.w);
        *(ushort4*)(Xb + i) = p0;
        *(ushort4*)(Xb + i + 4) = p1;
    } else if (b < 16384 + 3072) {
        int idx = (b - 16384) * 256 + threadIdx.x;   // 1536*512
        int n = idx >> 9, k = idx & 511;
        Wt1[idx] = f2b(qkv_w[(size_t)k * 1536 + n]);
    } else if (b < 16384 + 4096) {
        int idx = (b - 16384 - 3072) * 256 + threadIdx.x;  // 512*512
        int n = idx >> 9, k = idx & 511;
        Wt2[idx] = f2b(proj_w[(size_t)k * 512 + n]);
    } else {
        int idx = (b - 16384 - 4096) * 256 + threadIdx.x;  // 16*4096
        int h = idx >> 12, rc = idx & 4095;
        biasf[idx] = bias_t[rel[rc] * 16 + h];
    }
}

// ---- 256x256-tile BK=64 GEMM ----------------------------------------------
// C = A @ Bt^T (+bias), K=512 fixed (8 K-tiles of 64).
// MODE 0: A = xb row-major MxK; out -> QKV planes bf16.
// MODE 1: A = attn head-blocked [h][w][tok][32] (K-tile T = planes 2T,2T+1);
//         out -> fp32 rows (N=512).

#define MF1(av, bv, mi, nt)                                                   \
    acc[mi][nt] = __builtin_amdgcn_mfma_f32_16x16x32_bf16(av, bv,             \
                                                          acc[mi][nt], 0, 0, 0);
#define MF16(A4, mb, B4)                                                      \
    MF1(A4[0], B4[0], (mb)+0, 0) MF1(A4[0], B4[1], (mb)+0, 1)                 \
    MF1(A4[0], B4[2], (mb)+0, 2) MF1(A4[0], B4[3], (mb)+0, 3)                 \
    MF1(A4[1], B4[0], (mb)+1, 0) MF1(A4[1], B4[1], (mb)+1, 1)                 \
    MF1(A4[1], B4[2], (mb)+1, 2) MF1(A4[1], B4[3], (mb)+1, 3)                 \
    MF1(A4[2], B4[0], (mb)+2, 0) MF1(A4[2], B4[1], (mb)+2, 1)                 \
    MF1(A4[2], B4[2], (mb)+2, 2) MF1(A4[2], B4[3], (mb)+2, 3)                 \
    MF1(A4[3], B4[0], (mb)+3, 0) MF1(A4[3], B4[1], (mb)+3, 1)                 \
    MF1(A4[3], B4[2], (mb)+3, 2) MF1(A4[3], B4[3], (mb)+3, 3)

// A frag set: m-half mh, k-half kh from LDS slot base sb
#define ARD4(dst, sb, mh, kh)                                                 \
    dst[0] = *(const bx8*)((sb) + awoff + ((mh)*4+0)*2048 + aoffk##kh);       \
    dst[1] = *(const bx8*)((sb) + awoff + ((mh)*4+1)*2048 + aoffk##kh);       \
    dst[2] = *(const bx8*)((sb) + awoff + ((mh)*4+2)*2048 + aoffk##kh);       \
    dst[3] = *(const bx8*)((sb) + awoff + ((mh)*4+3)*2048 + aoffk##kh);
#define BRD4(dst, sb, kh)                                                     \
    dst[0] = *(const bx8*)((sb) + bwoff + 0*2048 + aoffk##kh);                \
    dst[1] = *(const bx8*)((sb) + bwoff + 1*2048 + aoffk##kh);                \
    dst[2] = *(const bx8*)((sb) + bwoff + 2*2048 + aoffk##kh);                \
    dst[3] = *(const bx8*)((sb) + bwoff + 3*2048 + aoffk##kh);

// one BK=64 tile: 4 phases x 16 MFMA, counted lgkm prefetch, 1 vmcnt+barrier
#define TILE64(T, DOST, LAST)                                                 \
    {                                                                         \
        const char* sb = smem + ((T) & 1) * 65536;                            \
        const char* sn = smem + (((T) + 1) & 1) * 65536;                      \
        /* P1: prefetch A(m1,k0); stage T+1; MFMA aC x b0 */                  \
        ARD4(aN, sb, 1, 0)                                                    \
        if (DOST) STAGE((T) + 1);                                             \
        asm volatile("s_waitcnt lgkmcnt(4)" ::: "memory");                    \
        __builtin_amdgcn_sched_barrier(0);                                    \
        __builtin_amdgcn_s_setprio(1);                                        \
        MF16(aC, 0, b0)                                                       \
        __builtin_amdgcn_s_setprio(0);                                        \
        /* P2: prefetch A(m0,k1)+B(k1); MFMA aN x b0 */                       \
        ARD4(aC, sb, 0, 1)                                                    \
        BRD4(b1, sb, 1)                                                       \
        asm volatile("s_waitcnt lgkmcnt(8)" ::: "memory");                    \
        __builtin_amdgcn_sched_barrier(0);                                    \
        __builtin_amdgcn_s_setprio(1);                                        \
        MF16(aN, 4, b0)                                                       \
        __builtin_amdgcn_s_setprio(0);                                        \
        /* P3: prefetch A(m1,k1); MFMA aC x b1 */                             \
        ARD4(aN, sb, 1, 1)                                                    \
        asm volatile("s_waitcnt lgkmcnt(4)" ::: "memory");                    \
        __builtin_amdgcn_sched_barrier(0);                                    \
        __builtin_amdgcn_s_setprio(1);                                        \
        MF16(aC, 0, b1)                                                       \
        __builtin_amdgcn_s_setprio(0);                                        \
        /* P4: tile boundary; load next tile's (m0,k0)+B(k0); MFMA aN x b1 */ \
        if (!(LAST)) {                                                        \
            asm volatile("s_waitcnt vmcnt(0)" ::: "memory");                  \
            asm volatile("s_barrier" ::: "memory");                           \
            ARD4(aC, sn, 0, 0)                                                \
            BRD4(b0, sn, 0)                                                   \
            asm volatile("s_waitcnt lgkmcnt(8)" ::: "memory");                \
        } else {                                                              \
            asm volatile("s_waitcnt lgkmcnt(0)" ::: "memory");                \
        }                                                                     \
        __builtin_amdgcn_sched_barrier(0);                                    \
        __builtin_amdgcn_s_setprio(1);                                        \
        MF16(aN, 4, b1)                                                       \
        __builtin_amdgcn_s_setprio(0);                                        \
    }

template <int MODE>
__global__ __launch_bounds__(512, 2) void gemm64_k(
    const u16* __restrict__ A, const u16* __restrict__ Bt,
    const float* __restrict__ bias, void* __restrict__ Out) {
    extern __shared__ __align__(16) char smem[];   // 131072 B dynamic
    const int tid = threadIdx.x;
    const int wave = tid >> 6, lane = tid & 63;
    const int l16 = lane & 15, quad = lane >> 4;
    const int wm = wave >> 2, wn = wave & 3;       // 2M x 4N wave grid

    // T1: bijective XCD swizzle (nwg % 8 == 0), m-major per chunk
    const int NT_COL = (MODE == 0) ? 6 : 2;
    const int NWG = (MODE == 0) ? 1536 : 512;
    const int bid = blockIdx.x;
    const int swz = (bid & 7) * (NWG >> 3) + (bid >> 3);
    const int m0 = (swz / NT_COL) << 8;
    const int n0 = (swz % NT_COL) << 8;

    // staging: rows are 64 bf16 = 128 B = 8 chunks of 16 B.
    // one glds call = 8 KB = 64 rows; wave w covers rows [8w,8w+8),
    // lane: row 8w+(l>>3), chunk l&7.
    // T2: LDS[r][c] = G[r][c ^ (r&7)] -> src chunk sc = (l&7)^(l>>3).
    const int sc = (lane & 7) ^ (lane >> 3);
    const int stoff = wave * 1024;                 // wave-uniform LDS base

    const u16* Abase;
    size_t aplaneSel = 0, aoff1[4];
    if (MODE == 0) {
        Abase = A + (size_t)(m0 + 8 * wave + (lane >> 3)) * 512 + sc * 8;
    } else {
        aplaneSel = (size_t)(sc >> 2) * 2097152;
#pragma unroll
        for (int ci = 0; ci < 4; ++ci)
            aoff1[ci] = (size_t)((m0 >> 6) + ci) * 2048 +
                        (8 * wave + (lane >> 3)) * 32 + (sc & 3) * 8;
    }
    const u16* Bbase = Bt + (size_t)(n0 + 8 * wave + (lane >> 3)) * 512 + sc * 8;

    auto STAGE = [&](int T) {
        char* sb = smem + (T & 1) * 65536;
        if (MODE == 0) {
            const u16* a = Abase + (size_t)T * 64;
#pragma unroll
            for (int ci = 0; ci < 4; ++ci)
                glds16(a + (size_t)ci * 32768, sb + ci * 8192 + stoff);
        } else {
            const u16* a = A + (size_t)(2 * T) * 2097152 + aplaneSel;
#pragma unroll
            for (int ci = 0; ci < 4; ++ci)
                glds16(a + aoff1[ci], sb + ci * 8192 + stoff);
        }
        const u16* bs = Bbase + (size_t)T * 64;
#pragma unroll
        for (int ci = 0; ci < 4; ++ci)
            glds16(bs + (size_t)ci * 32768, sb + 32768 + ci * 8192 + stoff);
    };

    // frag read offsets: row = strip*16+l16 (128 B rows),
    // chunk = (kh*4+quad) ^ (l16&7)
    const int awoff = wm * 16384;
    const int bwoff = 32768 + wn * 8192;
    const int aoffk0 = l16 * 128 + (((0 * 4 + quad) ^ (l16 & 7)) * 16);
    const int aoffk1 = l16 * 128 + (((1 * 4 + quad) ^ (l16 & 7)) * 16);

    f4_t acc[8][4];
#pragma unroll
    for (int i = 0; i < 8; ++i)
#pragma unroll
        for (int j = 0; j < 4; ++j) acc[i][j] = (f4_t){0.f, 0.f, 0.f, 0.f};

    bx8 aC[4], aN[4], b0[4], b1[4];

    // prologue: stage tile 0; retire; read (m0,k0)+B(k0)
    STAGE(0);
    asm volatile("s_waitcnt vmcnt(0)" ::: "memory");
    asm volatile("s_barrier" ::: "memory");
    {
        const char* sb = smem;
        ARD4(aC, sb, 0, 0)
        BRD4(b0, sb, 0)
    }

    TILE64(0, 1, 0)
    TILE64(1, 1, 0)
    TILE64(2, 1, 0)
    TILE64(3, 1, 0)
    TILE64(4, 1, 0)
    TILE64(5, 1, 0)
    TILE64(6, 1, 0)
    TILE64(7, 0, 1)

    __syncthreads();   // align + fence before LDS reuse in epilogue

    float bv[4];
#pragma unroll
    for (int nt = 0; nt < 4; ++nt) bv[nt] = bias[n0 + wn * 64 + nt * 16 + l16];

    if (MODE == 0) {
        // epilogue: LDS restage -> QKV planes, 1024 B/wave contiguous stores.
        // column layout is [head][which][d]: 96 = 3*32 cols per head.
        u16* c_s = (u16*)smem;          // [128][264] bf16
        u16* qkvp = (u16*)Out;
        const int cg = n0 + wave * 32;
        const int hh = cg / 96;
        const int which = (cg - hh * 96) >> 5;
        u16* plane = qkvp + (size_t)which * QKV_ELEMS + (size_t)hh * 2048;
#pragma unroll
        for (int p = 0; p < 2; ++p) {
            if (wm == p) {
#pragma unroll
                for (int mt = 0; mt < 8; ++mt)
#pragma unroll
                    for (int nt = 0; nt < 4; ++nt)
#pragma unroll
                        for (int i = 0; i < 4; ++i)
                            c_s[(mt * 16 + quad * 4 + i) * 264 +
                                wn * 64 + nt * 16 + l16] =
                                f2b(acc[mt][nt][i] + bv[nt]);
            }
            __syncthreads();
#pragma unroll
            for (int j = 0; j < 8; ++j) {
                int row = j * 16 + (lane >> 2);
                int gm = m0 + p * 128 + row;
                int w_win = gm >> 6, tok = gm & 63;
                uint4 v = *(const uint4*)&c_s[row * 264 + wave * 32 +
                                              (lane & 3) * 8];
                *(uint4*)(plane + (size_t)w_win * 32768 + tok * 32 +
                          (lane & 3) * 8) = v;
            }
            __syncthreads();
        }
    } else {
        // epilogue: fp32 rows, 4 passes of 64 rows, 1024 B/wave stores
        float* c_sf = (float*)smem;     // [64][264] fp32
        float* Of = (float*)Out;
#pragma unroll
        for (int p = 0; p < 4; ++p) {
            if (wm == (p >> 1)) {
                const int mtb = (p & 1) * 4;
#pragma unroll
                for (int mt2 = 0; mt2 < 4; ++mt2)
#pragma unroll
                    for (int nt = 0; nt < 4; ++nt)
#pragma unroll
                        for (int i = 0; i < 4; ++i)
                            c_sf[(mt2 * 16 + quad * 4 + i) * 264 +
                                 wn * 64 + nt * 16 + l16] =
                                acc[mtb + mt2][nt][i] + bv[nt];
            }
            __syncthreads();
#pragma unroll
            for (int j = 0; j < 8; ++j) {
                int flat = tid + 512 * j;           // 64 rows x 64 float4
                int r = flat >> 6, c4 = (flat & 63) * 4;
                float4 v = *(const float4*)&c_sf[r * 264 + c4];
                *(float4*)&Of[(size_t)(m0 + p * 64 + r) * 512 + n0 + c4] = v;
            }
            __syncthreads();
        }
    }
}

// ---- attention: 1 block per (window, head), 4 waves -----------------------
// LDS total 40704 B -> 4 blocks/CU
__global__ __launch_bounds__(256, 4) void attn_k(
    const u16* __restrict__ qkv, const float* __restrict__ mask,
    const float* __restrict__ biasf, u16* __restrict__ attn_out) {
    const int bx = blockIdx.x;
    const int w = bx >> 4, h = bx & 15;
    const int wmk = w & 255;  // mask window = b % 256
    const int tid = threadIdx.x;
    const int wave = tid >> 6, lane = tid & 63;
    const int quad = lane >> 4, l16 = lane & 15;

    __shared__ alignas(16) u16 q_s[64 * 40];
    __shared__ alignas(16) u16 k_s[64 * 40];
    __shared__ alignas(16) u16 vT[32 * 72];   // vT[d][tok]
    __shared__ alignas(16) float s_s[64 * 65];
    __shared__ alignas(16) u16 p_s[64 * 72];

    const size_t base = (size_t)((w << 4) + h) * 2048;  // 64*32 per (w,h)
    {
        int tok = tid >> 2, d0 = (tid & 3) * 8;
        uint4 qv = *(const uint4*)(qkv + base + tid * 8);
        *(uint4*)&q_s[tok * 40 + d0] = qv;
        uint4 kv = *(const uint4*)(qkv + QKV_ELEMS + base + tid * 8);
        *(uint4*)&k_s[tok * 40 + d0] = kv;
        uint4 vv = *(const uint4*)(qkv + 2 * QKV_ELEMS + base + tid * 8);
        const u16* pv = (const u16*)&vv;
#pragma unroll
        for (int j = 0; j < 8; ++j) vT[(d0 + j) * 72 + tok] = pv[j];
    }
    __syncthreads();

    // S = Q K^T * scale + bias + mask  (wave -> 16-row strip)
    {
        bx8 a = *(const bx8*)&q_s[(wave * 16 + l16) * 40 + quad * 8];
#pragma unroll
        for (int nt = 0; nt < 4; ++nt) {
            bx8 b = *(const bx8*)&k_s[(nt * 16 + l16) * 40 + quad * 8];
            f4_t acc = (f4_t){0.f, 0.f, 0.f, 0.f};
            acc = __builtin_amdgcn_mfma_f32_16x16x32_bf16(a, b, acc, 0, 0, 0);
#pragma unroll
            for (int i = 0; i < 4; ++i) {
                int r = wave * 16 + quad * 4 + i;
                int c = nt * 16 + l16;
                float s = acc[i] * SCALE + biasf[(h << 12) + (r << 6) + c] +
                          mask[((size_t)wmk * 64 + r) * 64 + c];
                s_s[r * 65 + c] = s;
            }
        }
    }
    __syncthreads();

    // row softmax: 4 threads per row, 16 cols each, shuffle-reduce
    {
        int row = tid >> 2, j = (tid & 3) * 16;
        float mx = -1e30f;
#pragma unroll
        for (int cc = 0; cc < 16; ++cc) mx = fmaxf(mx, s_s[row * 65 + j + cc]);
        mx = fmaxf(mx, __shfl_xor(mx, 1));
        mx = fmaxf(mx, __shfl_xor(mx, 2));
        float e[16], sum = 0.f;
#pragma unroll
        for (int cc = 0; cc < 16; ++cc) {
            e[cc] = __expf(s_s[row * 65 + j + cc] - mx);
            sum += e[cc];
        }
        sum += __shfl_xor(sum, 1);
        sum += __shfl_xor(sum, 2);
        float inv = 1.f / sum;
#pragma unroll
        for (int cc = 0; cc < 16; ++cc) p_s[row * 72 + j + cc] = f2b(e[cc] * inv);
    }
    __syncthreads();   // also fences s_s reads; s_s reused as O stage below

    // O = P V ; restage -> head-blocked [h][w][tok][d], coalesced uint4
    {
        u16* os = (u16*)s_s;   // [64][40]
#pragma unroll
        for (int nt = 0; nt < 2; ++nt) {
            f4_t acc = (f4_t){0.f, 0.f, 0.f, 0.f};
#pragma unroll
            for (int ks = 0; ks < 2; ++ks) {
                bx8 a = *(const bx8*)&p_s[(wave * 16 + l16) * 72 + ks * 32 + quad * 8];
                bx8 b = *(const bx8*)&vT[(nt * 16 + l16) * 72 + ks * 32 + quad * 8];
                acc = __builtin_amdgcn_mfma_f32_16x16x32_bf16(a, b, acc, 0, 0, 0);
            }
#pragma unroll
            for (int i = 0; i < 4; ++i)
                os[(wave * 16 + quad * 4 + i) * 40 + nt * 16 + l16] =
                    f2b(acc[i]);
        }
        __syncthreads();
        int tok = tid >> 2, d8 = (tid & 3) * 8;
        uint4 v = *(const uint4*)&os[tok * 40 + d8];
        *(uint4*)(attn_out + ((((size_t)h << 10) + w) << 11) + tid * 8) = v;
    }
}

extern "C" void kernel_launch(void* const* d_in, const int* in_sizes, int n_in,
                              void* d_out, int out_size, void* d_ws,
                              size_t ws_size, hipStream_t stream) {
    const float* x      = (const float*)d_in[0];
    const float* mask   = (const float*)d_in[1];
    const float* qkv_w  = (const float*)d_in[2];
    const float* qkv_b  = (const float*)d_in[3];
    const float* proj_w = (const float*)d_in[4];
    const float* proj_b = (const float*)d_in[5];
    const float* bias_t = (const float*)d_in[6];
    const int*   rel    = (const int*)d_in[7];
    float* out = (float*)d_out;

    char* ws = (char*)d_ws;
    u16* Wt1 = (u16*)ws;      ws += (size_t)1536 * 512 * 2;   // qkv_w^T bf16
    u16* Wt2 = (u16*)ws;      ws += (size_t)512 * 512 * 2;    // proj_w^T bf16
    float* biasf = (float*)ws; ws += (size_t)16 * 64 * 64 * 4; // bias_full
    u16* qkv = (u16*)ws;      ws += 3 * QKV_ELEMS * 2;        // Q,K,V planes
    u16* attn = (u16*)ws;     ws += QKV_ELEMS * 2;            // attn out bf16
    u16* xb = attn;  // alias: x_bf16 used only before attn_out is written

    // fused prep: cvt + qkv_w^T + proj_w^T + bias (16384+3072+1024+256)
    prep_k<<<20736, 256, 0, stream>>>(x, xb, qkv_w, Wt1, proj_w, Wt2,
                                      bias_t, rel, biasf);
    // QKV projection: M=65536, N=1536, K=512 (256x256 tiles, BK=64)
    gemm64_k<0><<<1536, 512, 131072, stream>>>(xb, Wt1, qkv_b, qkv);
    // window attention: 1024 windows x 16 heads
    attn_k<<<16384, 256, 0, stream>>>(qkv, mask, biasf, attn);
    // output projection: M=65536, N=512, K=512 (BK=64)
    gemm64_k<1><<<512, 512, 131072, stream>>>(attn, Wt2, proj_b, out);
}